// Round 5
// baseline (345.451 us; speedup 1.0000x reference)
//
#include <hip/hip_runtime.h>

// Problem constants
#define BATCH 4
#define SEQ 2048
#define DM 1024
#define NH 16
#define DK 64

typedef unsigned short u16;
typedef unsigned int u32;
typedef __attribute__((ext_vector_type(8))) short bfrag;    // 8 bf16 (MFMA x32 A/B)
typedef __attribute__((ext_vector_type(4))) short bfrag4;   // 4 bf16 (MFMA x16 A/B)
typedef __attribute__((ext_vector_type(4))) float ffrag;    // 4 fp32 (MFMA C/D)

__device__ inline u16 f2bf(float f) {
  union { float f; u32 u; } v; v.f = f;
  u32 u = v.u;
  return (u16)((u + 0x7FFFu + ((u >> 16) & 1u)) >> 16);  // RNE
}
__device__ inline float bf2f(u16 u) {
  union { u32 u; float f; } v; v.u = ((u32)u) << 16;
  return v.f;
}
__device__ inline ffrag MFMA(bfrag a, bfrag b, ffrag c) {
  return __builtin_amdgcn_mfma_f32_16x16x32_bf16(a, b, c, 0, 0, 0);
}
// mfma_f32_16x16x16bf16_1k: present in the DEVICE pass only (host __has_builtin
// is false — that's what broke R4). Host pass gets a type-check-only stub.
#if defined(__has_builtin)
#if __has_builtin(__builtin_amdgcn_mfma_f32_16x16x16bf16_1k)
#define HAVE_MFMA16 1
#endif
#endif
#if HAVE_MFMA16
__device__ inline ffrag MFMA16(bfrag4 a, bfrag4 b, ffrag c) {
  return __builtin_amdgcn_mfma_f32_16x16x16bf16_1k(a, b, c, 0, 0, 0);
}
#else
__device__ inline ffrag MFMA16(bfrag4 a, bfrag4 b, ffrag c) { return c; }  // host stub
#endif

// async global -> LDS, 16 bytes per lane (wave-uniform base + lane*16)
__device__ __forceinline__ void g2l16(const u16* g, u16* l) {
  __builtin_amdgcn_global_load_lds(
      (const __attribute__((address_space(1))) u16*)g,
      (__attribute__((address_space(3))) u16*)l, 16, 0, 0);
}

// ---------------- fp32 -> bf16 conversion
__global__ __launch_bounds__(256) void cvt_bf16(const float* __restrict__ in,
                                                u16* __restrict__ out, int n4) {
  int i = blockIdx.x * 256 + threadIdx.x;
  if (i >= n4) return;
  float4 v = ((const float4*)in)[i];
  union { u16 u[4]; uint2 d; } o;
  o.u[0] = f2bf(v.x); o.u[1] = f2bf(v.y); o.u[2] = f2bf(v.z); o.u[3] = f2bf(v.w);
  ((uint2*)out)[i] = o.d;
}

// fused 4-weight conversion
__global__ __launch_bounds__(256) void cvt_w4(
    const float* __restrict__ a, const float* __restrict__ b,
    const float* __restrict__ c, const float* __restrict__ d,
    u16* __restrict__ oa, u16* __restrict__ ob,
    u16* __restrict__ oc, u16* __restrict__ od) {
  int which = blockIdx.x >> 10;
  int i = (blockIdx.x & 1023) * 256 + threadIdx.x;
  const float* in = which == 0 ? a : which == 1 ? b : which == 2 ? c : d;
  u16* out = which == 0 ? oa : which == 1 ? ob : which == 2 ? oc : od;
  float4 v = ((const float4*)in)[i];
  union { u16 u[4]; uint2 dd; } o;
  o.u[0] = f2bf(v.x); o.u[1] = f2bf(v.y); o.u[2] = f2bf(v.z); o.u[3] = f2bf(v.w);
  ((uint2*)out)[i] = o.dd;
}

// ---------------- Q/K projection GEMM: y = x @ W^T, scatter to [B,H,S,DK] bf16
__global__ __launch_bounds__(256) void gemm_qkv(
    const u16* __restrict__ xb,
    const u16* __restrict__ Wq, const u16* __restrict__ Wk,
    u16* __restrict__ Qb, u16* __restrict__ Kb) {
  const u16* Bm; u16* O;
  if (blockIdx.z == 0) { Bm = Wq; O = Qb; }
  else { Bm = Wk; O = Kb; }

  const int K = DM;
  const int bm = blockIdx.y * 128, bn = blockIdx.x * 128;
  __shared__ __align__(16) u16 As[128 * 32];
  __shared__ __align__(16) u16 Bs[128 * 32];
  const int tid = threadIdx.x;
  const int lane = tid & 63;
  const int w = tid >> 6;
  const int wr = w >> 1, wc = w & 1;
  const int l15 = lane & 15, quad = lane >> 4;
  const int srow = tid >> 2, scol = (tid & 3) * 8;

  ffrag acc[4][4] = {};

  for (int k0 = 0; k0 < K; k0 += 32) {
    __syncthreads();
    g2l16(&xb[(size_t)(bm + srow) * K + k0 + scol], &As[tid * 8]);
    g2l16(&xb[(size_t)(bm + 64 + srow) * K + k0 + scol], &As[(tid + 256) * 8]);
    g2l16(&Bm[(size_t)(bn + srow) * K + k0 + scol], &Bs[tid * 8]);
    g2l16(&Bm[(size_t)(bn + 64 + srow) * K + k0 + scol], &Bs[(tid + 256) * 8]);
    __syncthreads();
    bfrag af[4], bf[4];
#pragma unroll
    for (int i = 0; i < 4; i++)
      af[i] = *(const bfrag*)(&As[(wr * 64 + i * 16 + l15) * 32 + quad * 8]);
#pragma unroll
    for (int j = 0; j < 4; j++)
      bf[j] = *(const bfrag*)(&Bs[(wc * 64 + j * 16 + l15) * 32 + quad * 8]);
#pragma unroll
    for (int i = 0; i < 4; i++)
#pragma unroll
      for (int j = 0; j < 4; j++)
        acc[i][j] = MFMA(af[i], bf[j], acc[i][j]);
  }

#pragma unroll
  for (int i = 0; i < 4; i++)
#pragma unroll
    for (int j = 0; j < 4; j++)
#pragma unroll
      for (int r = 0; r < 4; r++) {
        int m = bm + wr * 64 + i * 16 + quad * 4 + r;
        int n = bn + wc * 64 + j * 16 + l15;
        int b = m >> 11, s = m & 2047;
        int h = n >> 6, d = n & 63;
        O[(((size_t)(b * NH + h)) * SEQ + s) * DK + d] = f2bf(acc[i][j][r]);
      }
}

// ---------------- V projection with tile-swizzled transposed output.
// Per (b,h): 32 kv-tiles of 64; within a tile, element (d, s) lives at
// unit = ((d>>4)*4 + ((s>>4)&3))*64 + ((s>>2)&3)*16 + (d&15), offset unit*4+(s&3).
// This is the exact lane-linear image attn's PV A-fragments read (b64 at
// base + lane*8B) and is g2l16-stageable (contiguous per tile).
__global__ __launch_bounds__(256) void gemm_v(
    const u16* __restrict__ xb, const u16* __restrict__ Wv,
    u16* __restrict__ Vsw) {
  const int K = DM;
  const int bm = blockIdx.y * 128, bn = blockIdx.x * 128;  // bm tokens, bn out-dims
  __shared__ __align__(16) u16 As[128 * 32];
  __shared__ __align__(16) u16 Bs[128 * 32];
  const int tid = threadIdx.x;
  const int lane = tid & 63;
  const int w = tid >> 6;
  const int wr = w >> 1, wc = w & 1;
  const int l15 = lane & 15, quad = lane >> 4;
  const int srow = tid >> 2, scol = (tid & 3) * 8;

  ffrag acc[4][4] = {};   // [out-dim block][token block]

  for (int k0 = 0; k0 < K; k0 += 32) {
    __syncthreads();
    g2l16(&xb[(size_t)(bm + srow) * K + k0 + scol], &As[tid * 8]);
    g2l16(&xb[(size_t)(bm + 64 + srow) * K + k0 + scol], &As[(tid + 256) * 8]);
    g2l16(&Wv[(size_t)(bn + srow) * K + k0 + scol], &Bs[tid * 8]);
    g2l16(&Wv[(size_t)(bn + 64 + srow) * K + k0 + scol], &Bs[(tid + 256) * 8]);
    __syncthreads();
    bfrag af[4], bf[4];
#pragma unroll
    for (int i = 0; i < 4; i++)   // A = W (out-dims as m)
      af[i] = *(const bfrag*)(&Bs[(wr * 64 + i * 16 + l15) * 32 + quad * 8]);
#pragma unroll
    for (int j = 0; j < 4; j++)   // B = x^T (tokens as n)
      bf[j] = *(const bfrag*)(&As[(wc * 64 + j * 16 + l15) * 32 + quad * 8]);
#pragma unroll
    for (int i = 0; i < 4; i++)
#pragma unroll
      for (int j = 0; j < 4; j++)
        acc[i][j] = MFMA(af[i], bf[j], acc[i][j]);
  }

#pragma unroll
  for (int i = 0; i < 4; i++)
#pragma unroll
    for (int j = 0; j < 4; j++)
#pragma unroll
      for (int r = 0; r < 4; r++) {
        int n = bn + wr * 64 + i * 16 + quad * 4 + r;   // out-dim
        int m = bm + wc * 64 + j * 16 + l15;            // token
        int b = m >> 11, s = m & 2047;
        int h = n >> 6, d = n & 63;
        size_t hb = (size_t)(b * NH + h) * (SEQ * DK);
        size_t off = hb + (size_t)(s >> 6) * 4096 +
            ((((d >> 4) * 4 + ((s >> 4) & 3)) * 64 +
              ((s >> 2) & 3) * 16 + (d & 15)) * 4 + (s & 3));
        Vsw[off] = f2bf(acc[i][j][r]);
      }
}

// ---------------- out projection GEMM: out = Ab @ Wout^T, fp32 output
__global__ __launch_bounds__(256) void gemm_out(
    const u16* __restrict__ Ab, const u16* __restrict__ Wo, float* __restrict__ C) {
  const int K = DM, N = DM;
  const int bm = blockIdx.y * 128, bn = blockIdx.x * 128;
  __shared__ __align__(16) u16 As[128 * 32];
  __shared__ __align__(16) u16 Bs[128 * 32];
  const int tid = threadIdx.x;
  const int lane = tid & 63;
  const int w = tid >> 6;
  const int wr = w >> 1, wc = w & 1;
  const int l15 = lane & 15, quad = lane >> 4;
  const int srow = tid >> 2, scol = (tid & 3) * 8;

  ffrag acc[4][4] = {};

  for (int k0 = 0; k0 < K; k0 += 32) {
    __syncthreads();
    g2l16(&Ab[(size_t)(bm + srow) * K + k0 + scol], &As[tid * 8]);
    g2l16(&Ab[(size_t)(bm + 64 + srow) * K + k0 + scol], &As[(tid + 256) * 8]);
    g2l16(&Wo[(size_t)(bn + srow) * K + k0 + scol], &Bs[tid * 8]);
    g2l16(&Wo[(size_t)(bn + 64 + srow) * K + k0 + scol], &Bs[(tid + 256) * 8]);
    __syncthreads();
    bfrag af[4], bf[4];
#pragma unroll
    for (int i = 0; i < 4; i++)
      af[i] = *(const bfrag*)(&As[(wr * 64 + i * 16 + l15) * 32 + quad * 8]);
#pragma unroll
    for (int j = 0; j < 4; j++)
      bf[j] = *(const bfrag*)(&Bs[(wc * 64 + j * 16 + l15) * 32 + quad * 8]);
#pragma unroll
    for (int i = 0; i < 4; i++)
#pragma unroll
      for (int j = 0; j < 4; j++)
        acc[i][j] = MFMA(af[i], bf[j], acc[i][j]);
  }

#pragma unroll
  for (int i = 0; i < 4; i++)
#pragma unroll
    for (int j = 0; j < 4; j++)
#pragma unroll
      for (int r = 0; r < 4; r++) {
        int m = bm + wr * 64 + i * 16 + quad * 4 + r;
        int n = bn + wc * 64 + j * 16 + l15;
        C[(size_t)m * N + n] = acc[i][j][r];
      }
}

// ---------------- Flash attention.
// S^T = K.Q^T with K A-frags read DIRECT FROM GLOBAL (16x64B coalesced b128,
// L1/L2-resident tile, identical across the 4 waves). V staged via g2l16 DMA
// from the swizzled layout into a double buffer; PV A-frags are lane-linear
// b64 (conflict-free). P stays in registers (x16 MFMA). One barrier per tile;
// V prefetched one tile ahead. Max-free softmax (scores O(1)); P truncated to
// bf16, lsum accumulated from the same truncated values (bias cancels in O/l).
__global__ __launch_bounds__(256) void attn(
    const u16* __restrict__ Qb, const u16* __restrict__ Kb,
    const u16* __restrict__ Vsw, u16* __restrict__ Ab) {
  const int bh = blockIdx.y;
  const int b = bh >> 4, h = bh & 15;
  const int qbase = blockIdx.x * 128;
  const int tid = threadIdx.x;
  const int w = tid >> 6, lane = tid & 63;
  const int l15 = lane & 15, quad = lane >> 4;

  __shared__ __align__(16) u16 Vt[2][4096];   // 64x64 swizzled V tile, dbuf

  const size_t hbase = (size_t)bh * SEQ * DK;

  // Q fragments (B-operand: n=q=l15, k=d=quad*8+e) scaled by 0.125*log2e
  const float qscale = 0.125f * 1.4426950408889634f;
  bfrag q[2][2];
#pragma unroll
  for (int i = 0; i < 2; i++)
#pragma unroll
    for (int kk = 0; kk < 2; kk++) {
      bfrag t = *(const bfrag*)(&Qb[hbase +
          (size_t)(qbase + w * 32 + i * 16 + l15) * DK + kk * 32 + quad * 8]);
#pragma unroll
      for (int e = 0; e < 8; e++)
        q[i][kk][e] = (short)f2bf(bf2f((u16)t[e]) * qscale);
    }

  ffrag O[4][2] = {};      // O^T accs: [d-block][q-block]
  float lsum[2] = {0.f, 0.f};

  // prefetch V tile 0
  {
    const u16* src = &Vsw[hbase];
    g2l16(&src[tid * 8], &Vt[0][tid * 8]);
    g2l16(&src[2048 + tid * 8], &Vt[0][2048 + tid * 8]);
  }

  for (int t = 0; t < SEQ / 64; t++) {
    const int kv0 = t * 64;
    const int buf = t & 1;
    __syncthreads();   // V tile t staged; prior reads of buf^1 done
    if (t + 1 < SEQ / 64) {
      const u16* src = &Vsw[hbase + (size_t)(t + 1) * 4096];
      g2l16(&src[tid * 8], &Vt[buf ^ 1][tid * 8]);
      g2l16(&src[2048 + tid * 8], &Vt[buf ^ 1][2048 + tid * 8]);
    }

    bfrag4 pb[4][2];
#pragma unroll
    for (int j = 0; j < 4; j++) {     // kv 16-block
      // K A-frags direct from global: [kv0+j*16+l15][quad*8 .. +7]
      const u16* krow = &Kb[hbase + (size_t)(kv0 + j * 16 + l15) * DK + quad * 8];
      bfrag k0f = *(const bfrag*)(krow);
      bfrag k1f = *(const bfrag*)(krow + 32);
#pragma unroll
      for (int i = 0; i < 2; i++) {   // q 16-block
        ffrag z = {};
        z = MFMA(k0f, q[i][0], z);
        z = MFMA(k1f, q[i][1], z);    // S^T block: lane (q=l15, s=quad*4+r)
        u32 u[4]; float ts = 0.f;
#pragma unroll
        for (int r = 0; r < 4; r++) {
          float p = __builtin_amdgcn_exp2f(z[r]);
          u[r] = __float_as_uint(p);
          ts += __uint_as_float(u[r] & 0xffff0000u);
        }
        lsum[i] += ts;
        union { u32 d[2]; bfrag4 v; } pk;
        pk.d[0] = (u[1] & 0xffff0000u) | (u[0] >> 16);
        pk.d[1] = (u[3] & 0xffff0000u) | (u[2] >> 16);
        pb[j][i] = pk.v;
      }
    }

    // O^T += V^T . P^T : A-frags lane-linear b64 from swizzled V tile
#pragma unroll
    for (int j = 0; j < 4; j++)
#pragma unroll
      for (int db = 0; db < 4; db++) {
        bfrag4 vf = *(const bfrag4*)(&Vt[buf][((db * 4 + j) * 64 + lane) * 4]);
        O[db][0] = MFMA16(vf, pb[j][0], O[db][0]);
        O[db][1] = MFMA16(vf, pb[j][1], O[db][1]);
      }
  }

  // reduce lsum across the 4 quads (same q=l15)
  float rl[2];
#pragma unroll
  for (int i = 0; i < 2; i++) {
    float s = lsum[i];
    s += __shfl_xor(s, 16);
    s += __shfl_xor(s, 32);
    rl[i] = 1.0f / s;
  }

  // O^T C-layout: lane holds q=l15, d=quad*4+r. Pack 4 d (8B) per store.
  const size_t obase = ((size_t)b * SEQ) * DM + (size_t)h * DK;
#pragma unroll
  for (int db = 0; db < 4; db++)
#pragma unroll
    for (int i = 0; i < 2; i++) {
      int s = qbase + w * 32 + i * 16 + l15;
      union { u16 u[4]; uint2 d; } o;
#pragma unroll
      for (int r = 0; r < 4; r++) o.u[r] = f2bf(O[db][i][r] * rl[i]);
      *(uint2*)(&Ab[obase + (size_t)s * DM + db * 16 + quad * 4]) = o.d;
    }
}

extern "C" void kernel_launch(void* const* d_in, const int* in_sizes, int n_in,
                              void* d_out, int out_size, void* d_ws, size_t ws_size,
                              hipStream_t stream) {
  const float* x  = (const float*)d_in[0];
  const float* Wq = (const float*)d_in[1];
  const float* Wk = (const float*)d_in[2];
  const float* Wv = (const float*)d_in[3];
  const float* Wo = (const float*)d_in[4];
  float* out = (float*)d_out;

  char* ws = (char*)d_ws;
  u16* xb  = (u16*)(ws + 0);          // 16 MB
  u16* Wqb = (u16*)(ws + 16777216);
  u16* Wkb = (u16*)(ws + 18874368);
  u16* Wvb = (u16*)(ws + 20971520);
  u16* Wob = (u16*)(ws + 23068672);
  u16* Qb  = (u16*)(ws + 25165824);   // [B,H,S,DK]
  u16* Kb  = (u16*)(ws + 41943040);   // [B,H,S,DK]
  u16* Vsw = (u16*)(ws + 58720256);   // [B,H] x 32 tiles x swizzled 64x64
  u16* Ab  = (u16*)(ws + 75497472);   // [B,S,DM]
  const size_t NEED = 92274688;
  if (ws_size < NEED) return;

  cvt_bf16<<<8192, 256, 0, stream>>>(x, xb, (BATCH * SEQ * DM) / 4);
  cvt_w4<<<4096, 256, 0, stream>>>(Wq, Wk, Wv, Wo, Wqb, Wkb, Wvb, Wob);

  dim3 gqk(DM / 128, (BATCH * SEQ) / 128, 2);
  gemm_qkv<<<gqk, 256, 0, stream>>>(xb, Wqb, Wkb, Qb, Kb);
  dim3 gv(DM / 128, (BATCH * SEQ) / 128);
  gemm_v<<<gv, 256, 0, stream>>>(xb, Wvb, Vsw);

  dim3 gat(SEQ / 128, BATCH * NH);
  attn<<<gat, 256, 0, stream>>>(Qb, Kb, Vsw, Ab);

  dim3 gout(DM / 128, (BATCH * SEQ) / 128);
  gemm_out<<<gout, 256, 0, stream>>>(Ab, Wob, out);
}

// Round 6
// 299.506 us; speedup vs baseline: 1.1534x; 1.1534x over previous
//
#include <hip/hip_runtime.h>

// Problem constants
#define BATCH 4
#define SEQ 2048
#define DM 1024
#define NH 16
#define DK 64

typedef unsigned short u16;
typedef unsigned int u32;
typedef __attribute__((ext_vector_type(8))) short bfrag;    // 8 bf16 (MFMA x32 A/B)
typedef __attribute__((ext_vector_type(4))) short bfrag4;   // 4 bf16 (MFMA x16 A/B)
typedef __attribute__((ext_vector_type(4))) float ffrag;    // 4 fp32 (MFMA C/D)

__device__ inline u16 f2bf(float f) {
  union { float f; u32 u; } v; v.f = f;
  u32 u = v.u;
  return (u16)((u + 0x7FFFu + ((u >> 16) & 1u)) >> 16);  // RNE
}
__device__ inline float bf2f(u16 u) {
  union { u32 u; float f; } v; v.u = ((u32)u) << 16;
  return v.f;
}
__device__ inline ffrag MFMA(bfrag a, bfrag b, ffrag c) {
  return __builtin_amdgcn_mfma_f32_16x16x32_bf16(a, b, c, 0, 0, 0);
}
// Device pass only (host __has_builtin is false — R4 lesson). Host gets a stub.
#if defined(__has_builtin)
#if __has_builtin(__builtin_amdgcn_mfma_f32_16x16x16bf16_1k)
#define HAVE_MFMA16 1
#endif
#endif
#if HAVE_MFMA16
__device__ inline ffrag MFMA16(bfrag4 a, bfrag4 b, ffrag c) {
  return __builtin_amdgcn_mfma_f32_16x16x16bf16_1k(a, b, c, 0, 0, 0);
}
#else
__device__ inline ffrag MFMA16(bfrag4 a, bfrag4 b, ffrag c) { return c; }  // host stub
#endif

// async global -> LDS, 16 bytes per lane (wave-uniform base + lane*16)
__device__ __forceinline__ void g2l16(const u16* g, u16* l) {
  __builtin_amdgcn_global_load_lds(
      (const __attribute__((address_space(1))) u16*)g,
      (__attribute__((address_space(3))) u16*)l, 16, 0, 0);
}

// ---------------- fp32 -> bf16 conversion
__global__ __launch_bounds__(256) void cvt_bf16(const float* __restrict__ in,
                                                u16* __restrict__ out, int n4) {
  int i = blockIdx.x * 256 + threadIdx.x;
  if (i >= n4) return;
  float4 v = ((const float4*)in)[i];
  union { u16 u[4]; uint2 d; } o;
  o.u[0] = f2bf(v.x); o.u[1] = f2bf(v.y); o.u[2] = f2bf(v.z); o.u[3] = f2bf(v.w);
  ((uint2*)out)[i] = o.d;
}

// fused 4-weight conversion
__global__ __launch_bounds__(256) void cvt_w4(
    const float* __restrict__ a, const float* __restrict__ b,
    const float* __restrict__ c, const float* __restrict__ d,
    u16* __restrict__ oa, u16* __restrict__ ob,
    u16* __restrict__ oc, u16* __restrict__ od) {
  int which = blockIdx.x >> 10;
  int i = (blockIdx.x & 1023) * 256 + threadIdx.x;
  const float* in = which == 0 ? a : which == 1 ? b : which == 2 ? c : d;
  u16* out = which == 0 ? oa : which == 1 ? ob : which == 2 ? oc : od;
  float4 v = ((const float4*)in)[i];
  union { u16 u[4]; uint2 dd; } o;
  o.u[0] = f2bf(v.x); o.u[1] = f2bf(v.y); o.u[2] = f2bf(v.z); o.u[3] = f2bf(v.w);
  ((uint2*)out)[i] = o.dd;
}

// ---------------- fused Q/K/V projection. z=0: Q row-layout [B,H,S,DK].
// z=1: K swizzled per 64-kv tile: frag (j=(s>>4)&3, half=d>>5) for lane
// (quad=(d>>3)&3, l15=s&15) at ((j*2+half)*64 + quad*16 + l15)*8 + (d&7).
// z=2: V^T swizzled (computed with swapped operand roles): element (d,s) at
// unit=((d>>4)*4+((s>>4)&3))*64 + ((s>>2)&3)*16 + (d&15), offset unit*4+(s&3).
// Both swizzles are the exact lane-linear images attn's fragments read, so
// attn can stage them with pure g2l16 DMA and read conflict-free.
__global__ __launch_bounds__(256) void gemm_qkv(
    const u16* __restrict__ xb,
    const u16* __restrict__ Wq, const u16* __restrict__ Wk,
    const u16* __restrict__ Wv,
    u16* __restrict__ Qb, u16* __restrict__ Ksw, u16* __restrict__ Vsw) {
  const int z = blockIdx.z;
  const u16* Bm = z == 0 ? Wq : z == 1 ? Wk : Wv;

  const int K = DM;
  const int bm = blockIdx.y * 128, bn = blockIdx.x * 128;
  __shared__ __align__(16) u16 As[128 * 32];
  __shared__ __align__(16) u16 Bs[128 * 32];
  const int tid = threadIdx.x;
  const int lane = tid & 63;
  const int w = tid >> 6;
  const int wr = w >> 1, wc = w & 1;
  const int l15 = lane & 15, quad = lane >> 4;
  const int srow = tid >> 2, scol = (tid & 3) * 8;

  ffrag acc[4][4] = {};

  for (int k0 = 0; k0 < K; k0 += 32) {
    __syncthreads();
    g2l16(&xb[(size_t)(bm + srow) * K + k0 + scol], &As[tid * 8]);
    g2l16(&xb[(size_t)(bm + 64 + srow) * K + k0 + scol], &As[(tid + 256) * 8]);
    g2l16(&Bm[(size_t)(bn + srow) * K + k0 + scol], &Bs[tid * 8]);
    g2l16(&Bm[(size_t)(bn + 64 + srow) * K + k0 + scol], &Bs[(tid + 256) * 8]);
    __syncthreads();
    bfrag af[4], bf[4];
    if (z < 2) {
#pragma unroll
      for (int i = 0; i < 4; i++)
        af[i] = *(const bfrag*)(&As[(wr * 64 + i * 16 + l15) * 32 + quad * 8]);
#pragma unroll
      for (int j = 0; j < 4; j++)
        bf[j] = *(const bfrag*)(&Bs[(wc * 64 + j * 16 + l15) * 32 + quad * 8]);
    } else {   // V: A = W (out-dims as m), B = x^T (tokens as n)
#pragma unroll
      for (int i = 0; i < 4; i++)
        af[i] = *(const bfrag*)(&Bs[(wr * 64 + i * 16 + l15) * 32 + quad * 8]);
#pragma unroll
      for (int j = 0; j < 4; j++)
        bf[j] = *(const bfrag*)(&As[(wc * 64 + j * 16 + l15) * 32 + quad * 8]);
    }
#pragma unroll
    for (int i = 0; i < 4; i++)
#pragma unroll
      for (int j = 0; j < 4; j++)
        acc[i][j] = MFMA(af[i], bf[j], acc[i][j]);
  }

  if (z == 0) {
#pragma unroll
    for (int i = 0; i < 4; i++)
#pragma unroll
      for (int j = 0; j < 4; j++)
#pragma unroll
        for (int r = 0; r < 4; r++) {
          int m = bm + wr * 64 + i * 16 + quad * 4 + r;
          int n = bn + wc * 64 + j * 16 + l15;
          int b = m >> 11, s = m & 2047;
          int h = n >> 6, d = n & 63;
          Qb[(((size_t)(b * NH + h)) * SEQ + s) * DK + d] = f2bf(acc[i][j][r]);
        }
  } else if (z == 1) {
#pragma unroll
    for (int i = 0; i < 4; i++)
#pragma unroll
      for (int j = 0; j < 4; j++)
#pragma unroll
        for (int r = 0; r < 4; r++) {
          int m = bm + wr * 64 + i * 16 + quad * 4 + r;
          int n = bn + wc * 64 + j * 16 + l15;
          int b = m >> 11, s = m & 2047;
          int h = n >> 6, d = n & 63;
          size_t hb = (size_t)(b * NH + h) * (SEQ * DK);
          size_t off = hb + (size_t)(s >> 6) * 4096 +
              ((((s >> 4) & 3) * 2 + (d >> 5)) * 64 +
               ((d >> 3) & 3) * 16 + (s & 15)) * 8 + (d & 7);
          Ksw[off] = f2bf(acc[i][j][r]);
        }
  } else {
#pragma unroll
    for (int i = 0; i < 4; i++)
#pragma unroll
      for (int j = 0; j < 4; j++)
#pragma unroll
        for (int r = 0; r < 4; r++) {
          int n = bn + wr * 64 + i * 16 + quad * 4 + r;   // out-dim
          int m = bm + wc * 64 + j * 16 + l15;            // token
          int b = m >> 11, s = m & 2047;
          int h = n >> 6, d = n & 63;
          size_t hb = (size_t)(b * NH + h) * (SEQ * DK);
          size_t off = hb + (size_t)(s >> 6) * 4096 +
              ((((d >> 4) * 4 + ((s >> 4) & 3)) * 64 +
                ((s >> 2) & 3) * 16 + (d & 15)) * 4 + (s & 3));
          Vsw[off] = f2bf(acc[i][j][r]);
        }
  }
}

// ---------------- out projection GEMM: out = Ab @ Wout^T, fp32 output
__global__ __launch_bounds__(256) void gemm_out(
    const u16* __restrict__ Ab, const u16* __restrict__ Wo, float* __restrict__ C) {
  const int K = DM, N = DM;
  const int bm = blockIdx.y * 128, bn = blockIdx.x * 128;
  __shared__ __align__(16) u16 As[128 * 32];
  __shared__ __align__(16) u16 Bs[128 * 32];
  const int tid = threadIdx.x;
  const int lane = tid & 63;
  const int w = tid >> 6;
  const int wr = w >> 1, wc = w & 1;
  const int l15 = lane & 15, quad = lane >> 4;
  const int srow = tid >> 2, scol = (tid & 3) * 8;

  ffrag acc[4][4] = {};

  for (int k0 = 0; k0 < K; k0 += 32) {
    __syncthreads();
    g2l16(&Ab[(size_t)(bm + srow) * K + k0 + scol], &As[tid * 8]);
    g2l16(&Ab[(size_t)(bm + 64 + srow) * K + k0 + scol], &As[(tid + 256) * 8]);
    g2l16(&Wo[(size_t)(bn + srow) * K + k0 + scol], &Bs[tid * 8]);
    g2l16(&Wo[(size_t)(bn + 64 + srow) * K + k0 + scol], &Bs[(tid + 256) * 8]);
    __syncthreads();
    bfrag af[4], bf[4];
#pragma unroll
    for (int i = 0; i < 4; i++)
      af[i] = *(const bfrag*)(&As[(wr * 64 + i * 16 + l15) * 32 + quad * 8]);
#pragma unroll
    for (int j = 0; j < 4; j++)
      bf[j] = *(const bfrag*)(&Bs[(wc * 64 + j * 16 + l15) * 32 + quad * 8]);
#pragma unroll
    for (int i = 0; i < 4; i++)
#pragma unroll
      for (int j = 0; j < 4; j++)
        acc[i][j] = MFMA(af[i], bf[j], acc[i][j]);
  }

#pragma unroll
  for (int i = 0; i < 4; i++)
#pragma unroll
    for (int j = 0; j < 4; j++)
#pragma unroll
      for (int r = 0; r < 4; r++) {
        int m = bm + wr * 64 + i * 16 + quad * 4 + r;
        int n = bn + wc * 64 + j * 16 + l15;
        C[(size_t)m * N + n] = acc[i][j][r];
      }
}

// ---------------- Flash attention.
// K and V both staged via g2l16 DMA from swizzled global layouts into double
// buffers; compute phase reads ONLY LDS (lane-linear, conflict-free), so the
// single per-tile barrier is the only vmcnt wait and DMA(t+1) overlaps the
// whole compute(t) (R5 lesson: any mid-loop global read drains the DMA queue).
// S^T = K.Q^T (x32 MFMA); P stays in registers; O^T += V^T.P^T (x16 MFMA).
// Max-free softmax; P truncated to bf16, lsum from the same truncated values.
__global__ __launch_bounds__(256) void attn(
    const u16* __restrict__ Qb, const u16* __restrict__ Ksw,
    const u16* __restrict__ Vsw, u16* __restrict__ Ab) {
  const int bh = blockIdx.y;
  const int b = bh >> 4, h = bh & 15;
  const int qbase = blockIdx.x * 128;
  const int tid = threadIdx.x;
  const int w = tid >> 6, lane = tid & 63;
  const int l15 = lane & 15, quad = lane >> 4;

  __shared__ __align__(16) u16 Kt[2][4096];   // swizzled 64x64 K tile, dbuf
  __shared__ __align__(16) u16 Vt[2][4096];   // swizzled 64x64 V tile, dbuf

  const size_t hbase = (size_t)bh * SEQ * DK;

  // Q fragments (B-operand: n=q=l15, k=d=quad*8+e) scaled by 0.125*log2e
  const float qscale = 0.125f * 1.4426950408889634f;
  bfrag q[2][2];
#pragma unroll
  for (int i = 0; i < 2; i++)
#pragma unroll
    for (int kk = 0; kk < 2; kk++) {
      bfrag t = *(const bfrag*)(&Qb[hbase +
          (size_t)(qbase + w * 32 + i * 16 + l15) * DK + kk * 32 + quad * 8]);
#pragma unroll
      for (int e = 0; e < 8; e++)
        q[i][kk][e] = (short)f2bf(bf2f((u16)t[e]) * qscale);
    }

  ffrag O[4][2] = {};      // O^T accs: [d-block][q-block]
  float lsum[2] = {0.f, 0.f};

  // prefetch tile 0 (K: 8KB = 2 DMA calls; V: 8KB = 2 DMA calls)
  {
    const u16* ks = &Ksw[hbase];
    const u16* vs = &Vsw[hbase];
    g2l16(&ks[tid * 8], &Kt[0][tid * 8]);
    g2l16(&ks[2048 + tid * 8], &Kt[0][2048 + tid * 8]);
    g2l16(&vs[tid * 8], &Vt[0][tid * 8]);
    g2l16(&vs[2048 + tid * 8], &Vt[0][2048 + tid * 8]);
  }

  for (int t = 0; t < SEQ / 64; t++) {
    const int buf = t & 1;
    __syncthreads();   // DMA for tile t complete; prior reads of buf^1 done
    if (t + 1 < SEQ / 64) {
      const u16* ks = &Ksw[hbase + (size_t)(t + 1) * 4096];
      const u16* vs = &Vsw[hbase + (size_t)(t + 1) * 4096];
      g2l16(&ks[tid * 8], &Kt[buf ^ 1][tid * 8]);
      g2l16(&ks[2048 + tid * 8], &Kt[buf ^ 1][2048 + tid * 8]);
      g2l16(&vs[tid * 8], &Vt[buf ^ 1][tid * 8]);
      g2l16(&vs[2048 + tid * 8], &Vt[buf ^ 1][2048 + tid * 8]);
    }

    bfrag4 pb[4][2];
#pragma unroll
    for (int j = 0; j < 4; j++) {     // kv 16-block
      bfrag k0f = *(const bfrag*)(&Kt[buf][((j * 2 + 0) * 64 + lane) * 8]);
      bfrag k1f = *(const bfrag*)(&Kt[buf][((j * 2 + 1) * 64 + lane) * 8]);
#pragma unroll
      for (int i = 0; i < 2; i++) {   // q 16-block
        ffrag z = {};
        z = MFMA(k0f, q[i][0], z);
        z = MFMA(k1f, q[i][1], z);    // S^T block: lane (q=l15, s=quad*4+r)
        u32 u[4]; float ts = 0.f;
#pragma unroll
        for (int r = 0; r < 4; r++) {
          float p = __builtin_amdgcn_exp2f(z[r]);
          u[r] = __float_as_uint(p);
          ts += __uint_as_float(u[r] & 0xffff0000u);
        }
        lsum[i] += ts;
        union { u32 d[2]; bfrag4 v; } pk;
        pk.d[0] = (u[1] & 0xffff0000u) | (u[0] >> 16);
        pk.d[1] = (u[3] & 0xffff0000u) | (u[2] >> 16);
        pb[j][i] = pk.v;
      }
    }

    // O^T += V^T . P^T : A-frags lane-linear b64 from swizzled V tile
#pragma unroll
    for (int j = 0; j < 4; j++)
#pragma unroll
      for (int db = 0; db < 4; db++) {
        bfrag4 vf = *(const bfrag4*)(&Vt[buf][((db * 4 + j) * 64 + lane) * 4]);
        O[db][0] = MFMA16(vf, pb[j][0], O[db][0]);
        O[db][1] = MFMA16(vf, pb[j][1], O[db][1]);
      }
  }

  // reduce lsum across the 4 quads (same q=l15)
  float rl[2];
#pragma unroll
  for (int i = 0; i < 2; i++) {
    float s = lsum[i];
    s += __shfl_xor(s, 16);
    s += __shfl_xor(s, 32);
    rl[i] = 1.0f / s;
  }

  // O^T C-layout: lane holds q=l15, d=quad*4+r. Pack 4 d (8B) per store.
  const size_t obase = ((size_t)b * SEQ) * DM + (size_t)h * DK;
#pragma unroll
  for (int db = 0; db < 4; db++)
#pragma unroll
    for (int i = 0; i < 2; i++) {
      int s = qbase + w * 32 + i * 16 + l15;
      union { u16 u[4]; uint2 d; } o;
#pragma unroll
      for (int r = 0; r < 4; r++) o.u[r] = f2bf(O[db][i][r] * rl[i]);
      *(uint2*)(&Ab[obase + (size_t)s * DM + db * 16 + quad * 4]) = o.d;
    }
}

extern "C" void kernel_launch(void* const* d_in, const int* in_sizes, int n_in,
                              void* d_out, int out_size, void* d_ws, size_t ws_size,
                              hipStream_t stream) {
  const float* x  = (const float*)d_in[0];
  const float* Wq = (const float*)d_in[1];
  const float* Wk = (const float*)d_in[2];
  const float* Wv = (const float*)d_in[3];
  const float* Wo = (const float*)d_in[4];
  float* out = (float*)d_out;

  char* ws = (char*)d_ws;
  u16* xb  = (u16*)(ws + 0);          // 16 MB
  u16* Wqb = (u16*)(ws + 16777216);
  u16* Wkb = (u16*)(ws + 18874368);
  u16* Wvb = (u16*)(ws + 20971520);
  u16* Wob = (u16*)(ws + 23068672);
  u16* Qb  = (u16*)(ws + 25165824);   // [B,H,S,DK]
  u16* Ksw = (u16*)(ws + 41943040);   // [B,H] x 32 tiles x swizzled 64x64
  u16* Vsw = (u16*)(ws + 58720256);   // [B,H] x 32 tiles x swizzled 64x64
  u16* Ab  = (u16*)(ws + 75497472);   // [B,S,DM]
  const size_t NEED = 92274688;
  if (ws_size < NEED) return;

  cvt_bf16<<<8192, 256, 0, stream>>>(x, xb, (BATCH * SEQ * DM) / 4);
  cvt_w4<<<4096, 256, 0, stream>>>(Wq, Wk, Wv, Wo, Wqb, Wkb, Wvb, Wob);

  dim3 gqkv(DM / 128, (BATCH * SEQ) / 128, 3);
  gemm_qkv<<<gqkv, 256, 0, stream>>>(xb, Wqb, Wkb, Wvb, Qb, Ksw, Vsw);

  dim3 gat(SEQ / 128, BATCH * NH);
  attn<<<gat, 256, 0, stream>>>(Qb, Ksw, Vsw, Ab);

  dim3 gout(DM / 128, (BATCH * SEQ) / 128);
  gemm_out<<<gout, 256, 0, stream>>>(Ab, Wob, out);
}